// Round 1
// baseline (751.225 us; speedup 1.0000x reference)
//
#include <hip/hip_runtime.h>
#include <hip/hip_bf16.h>
#include <stdint.h>

#define H_    12
#define B_    512
#define S_    80
#define D_    768
#define NQKV  2304
#define DH    64

typedef __bf16 bf16x8 __attribute__((ext_vector_type(8)));
typedef float  f32x4  __attribute__((ext_vector_type(4)));
typedef unsigned short u16;
typedef unsigned int   u32;

__device__ __forceinline__ u16 f2bf(float f) {
    u32 u = __builtin_bit_cast(u32, f);
    u32 r = u + 0x7FFFu + ((u >> 16) & 1u);
    return (u16)(r >> 16);
}
__device__ __forceinline__ float bf2f(u16 h) {
    u32 u = ((u32)h) << 16;
    return __builtin_bit_cast(float, u);
}

// ---------------- prep: pack W^T (bf16), bias (f32), rope tables ----------------
__global__ void prep_kernel(const float* __restrict__ Wq, const float* __restrict__ bq,
                            const float* __restrict__ Wk, const float* __restrict__ bk,
                            const float* __restrict__ Wv, const float* __restrict__ bv,
                            u16* __restrict__ Wt, float* __restrict__ biasf,
                            float* __restrict__ ropeS, float* __restrict__ ropeC) {
    int idx = blockIdx.x * blockDim.x + threadIdx.x;
    int stride = gridDim.x * blockDim.x;
    // Wt[n][k] = W[k][n%768]  (n: 0..767 -> Wq, 768..1535 -> Wk, else Wv)
    for (int i = idx; i < NQKV * D_; i += stride) {
        int n = i / D_;
        int k = i - n * D_;
        const float* W; int nn;
        if (n < D_)          { W = Wq; nn = n; }
        else if (n < 2 * D_) { W = Wk; nn = n - D_; }
        else                 { W = Wv; nn = n - 2 * D_; }
        Wt[i] = f2bf(W[k * D_ + nn]);
    }
    for (int i = idx; i < NQKV; i += stride) {
        const float* bsrc; int nn;
        if (i < D_)          { bsrc = bq; nn = i; }
        else if (i < 2 * D_) { bsrc = bk; nn = i - D_; }
        else                 { bsrc = bv; nn = i - 2 * D_; }
        biasf[i] = bsrc[nn];
    }
    for (int i = idx; i < S_ * 32; i += stride) {
        int pos = i >> 5, fi = i & 31;
        float invf = powf(10000.0f, -(float)fi / 32.0f);
        float fr = (float)pos * invf;
        ropeS[i] = sinf(fr);
        ropeC[i] = cosf(fr);
    }
}

// ---------------- fused QKV GEMM: Y[40960][2304] = bf16(X @ [Wq|Wk|Wv] + b) ----------------
#define BM 128
#define BN 128
#define BK 64
#define LDA 72   // padded LDS row stride (bf16 elems): 144B -> 2-way bank conflict only

__global__ __launch_bounds__(256, 2) void qkv_gemm(
    const float* __restrict__ X,     // [40960][768] f32
    const u16*   __restrict__ Wt,    // [2304][768] bf16 (N-major = B^T)
    const float* __restrict__ biasf, // [2304]
    u16*         __restrict__ Y)     // [40960][2304] bf16
{
    __shared__ alignas(16) u16 As[BM * LDA];
    __shared__ alignas(16) u16 Bs[BN * LDA];
    const int m0 = blockIdx.y * BM;
    const int n0 = blockIdx.x * BN;
    const int tid = threadIdx.x;
    const int lane = tid & 63;
    const int w  = tid >> 6;        // wave 0..3
    const int wr = (w >> 1) * 64;   // wave sub-tile row
    const int wc = (w & 1) * 64;    // wave sub-tile col
    const int lr = lane & 15;
    const int lg = lane >> 4;

    f32x4 acc[4][4] = {};

    const int ar = tid >> 4;          // A stage: row base 0..15 (16 rows/pass)
    const int ac = (tid & 15) * 4;    // A stage: col (float4)
    const int bn = tid >> 3;          // B stage: row base 0..31 (32 rows/pass)
    const int bc = (tid & 7) * 8;     // B stage: col (8 bf16)

    for (int kt = 0; kt < D_ / BK; ++kt) {
        const int k0 = kt * BK;
        float4 av[8];
#pragma unroll
        for (int p = 0; p < 8; ++p)
            av[p] = *reinterpret_cast<const float4*>(&X[(size_t)(m0 + p * 16 + ar) * D_ + k0 + ac]);
        uint4 bv4[4];
#pragma unroll
        for (int p = 0; p < 4; ++p)
            bv4[p] = *reinterpret_cast<const uint4*>(&Wt[(size_t)(n0 + p * 32 + bn) * D_ + k0 + bc]);

        __syncthreads();   // prior iteration's LDS reads done
#pragma unroll
        for (int p = 0; p < 8; ++p) {
            uint2 u;
            u.x = (u32)f2bf(av[p].x) | ((u32)f2bf(av[p].y) << 16);
            u.y = (u32)f2bf(av[p].z) | ((u32)f2bf(av[p].w) << 16);
            *reinterpret_cast<uint2*>(&As[(p * 16 + ar) * LDA + ac]) = u;
        }
#pragma unroll
        for (int p = 0; p < 4; ++p)
            *reinterpret_cast<uint4*>(&Bs[(p * 32 + bn) * LDA + bc]) = bv4[p];
        __syncthreads();

        bf16x8 af[2][4], bf[2][4];
#pragma unroll
        for (int kk = 0; kk < 2; ++kk) {
#pragma unroll
            for (int i = 0; i < 4; ++i) {
                af[kk][i] = *reinterpret_cast<const bf16x8*>(&As[(wr + i * 16 + lr) * LDA + kk * 32 + lg * 8]);
                bf[kk][i] = *reinterpret_cast<const bf16x8*>(&Bs[(wc + i * 16 + lr) * LDA + kk * 32 + lg * 8]);
            }
        }
#pragma unroll
        for (int kk = 0; kk < 2; ++kk)
#pragma unroll
            for (int i = 0; i < 4; ++i)
#pragma unroll
                for (int j = 0; j < 4; ++j)
                    acc[i][j] = __builtin_amdgcn_mfma_f32_16x16x32_bf16(af[kk][i], bf[kk][j], acc[i][j], 0, 0, 0);
    }

    // epilogue: bias + bf16 store (C layout: col=lane&15, row=(lane>>4)*4+r)
#pragma unroll
    for (int j = 0; j < 4; ++j) {
        int col = n0 + wc + j * 16 + lr;
        float bval = biasf[col];
#pragma unroll
        for (int i = 0; i < 4; ++i) {
            int row = m0 + wr + i * 16 + lg * 4;
#pragma unroll
            for (int r = 0; r < 4; ++r)
                Y[(size_t)(row + r) * NQKV + col] = f2bf(acc[i][j][r] + bval);
        }
    }
}

// ---------------- attention: one block per (b,h), 5 waves (16 q-rows each) ----------------
#define LQ 72    // LDS row stride for Q/K (64 + 8 pad)
#define LV 104   // LDS row stride for Vt/P (96 zero-padded K + 8 pad)

__global__ __launch_bounds__(320) void attn_kernel(
    const u16* __restrict__ Y,      // [40960][2304] bf16 QKV
    const int* __restrict__ mask,   // [512][80]
    const float* __restrict__ ropeS,
    const float* __restrict__ ropeC,
    float* __restrict__ out)        // [40960][768] f32
{
    __shared__ alignas(16) u16 Qs[S_ * LQ];
    __shared__ alignas(16) u16 Ks[S_ * LQ];
    __shared__ alignas(16) u16 Vt[DH * LV];
    __shared__ alignas(16) u16 Ps[5 * 16 * LV];
    __shared__ float biasS[S_];

    const int h = blockIdx.x;
    const int b = blockIdx.y;
    const int tid = threadIdx.x;
    const size_t rowbase = (size_t)b * S_ * NQKV;

    // stage Q (rope + 1/sqrt(dh)) and K (rope)
    for (int p = tid; p < S_ * 32; p += 320) {
        int q = p >> 5, i2 = p & 31;
        u32 uq = *reinterpret_cast<const u32*>(&Y[rowbase + (size_t)q * NQKV + h * DH + 2 * i2]);
        u32 uk = *reinterpret_cast<const u32*>(&Y[rowbase + (size_t)q * NQKV + D_ + h * DH + 2 * i2]);
        float sn = ropeS[p], cs = ropeC[p];
        float q1 = bf2f((u16)(uq & 0xffff)), q2 = bf2f((u16)(uq >> 16));
        float k1 = bf2f((u16)(uk & 0xffff)), k2 = bf2f((u16)(uk >> 16));
        float o1 = (q1 * cs - q2 * sn) * 0.125f;
        float o2 = (q2 * cs + q1 * sn) * 0.125f;
        *reinterpret_cast<u32*>(&Qs[q * LQ + 2 * i2]) = (u32)f2bf(o1) | ((u32)f2bf(o2) << 16);
        o1 = k1 * cs - k2 * sn;
        o2 = k2 * cs + k1 * sn;
        *reinterpret_cast<u32*>(&Ks[q * LQ + 2 * i2]) = (u32)f2bf(o1) | ((u32)f2bf(o2) << 16);
    }
    // stage V transposed: Vt[c][s]
    for (int e = tid; e < S_ * DH; e += 320) {
        int s = e >> 6, c = e & 63;
        Vt[c * LV + s] = Y[rowbase + (size_t)s * NQKV + 2 * D_ + h * DH + c];
    }
    // zero pads: Vt cols 80..103, all of Ps
    for (int e = tid; e < DH * (LV - S_); e += 320) {
        int c = e / (LV - S_), kk = e % (LV - S_);
        Vt[c * LV + S_ + kk] = 0;
    }
    for (int e = tid; e < 5 * 16 * LV; e += 320) Ps[e] = 0;
    for (int e = tid; e < S_; e += 320)
        biasS[e] = (1.0f - (float)mask[b * S_ + e]) * -10000.0f;
    __syncthreads();

    const int wv = tid >> 6;   // stripe 0..4
    const int lane = tid & 63;
    const int lr = lane & 15;
    const int lg = lane >> 4;

    // scores: S = (Q/8) K^T  (16 x 80 per wave)
    f32x4 sc[5] = {};
    bf16x8 aq[2];
#pragma unroll
    for (int kk = 0; kk < 2; ++kk)
        aq[kk] = *reinterpret_cast<const bf16x8*>(&Qs[(wv * 16 + lr) * LQ + kk * 32 + lg * 8]);
#pragma unroll
    for (int t = 0; t < 5; ++t) {
#pragma unroll
        for (int kk = 0; kk < 2; ++kk) {
            bf16x8 bk8 = *reinterpret_cast<const bf16x8*>(&Ks[(t * 16 + lr) * LQ + kk * 32 + lg * 8]);
            sc[t] = __builtin_amdgcn_mfma_f32_16x16x32_bf16(aq[kk], bk8, sc[t], 0, 0, 0);
        }
    }
    // mask bias + softmax per row (4 rows/lane), reductions across 16 lanes
#pragma unroll
    for (int j = 0; j < 4; ++j) {
        float m = -1e30f;
#pragma unroll
        for (int t = 0; t < 5; ++t) { sc[t][j] += biasS[t * 16 + lr]; m = fmaxf(m, sc[t][j]); }
#pragma unroll
        for (int msk = 1; msk < 16; msk <<= 1) m = fmaxf(m, __shfl_xor(m, msk));
        float s = 0.f;
#pragma unroll
        for (int t = 0; t < 5; ++t) { float e = __expf(sc[t][j] - m); sc[t][j] = e; s += e; }
#pragma unroll
        for (int msk = 1; msk < 16; msk <<= 1) s += __shfl_xor(s, msk);
        float ri = 1.0f / s;
#pragma unroll
        for (int t = 0; t < 5; ++t) sc[t][j] *= ri;
    }
    // P -> LDS bf16 (cols 80..95 stay zero)
#pragma unroll
    for (int t = 0; t < 5; ++t)
#pragma unroll
        for (int j = 0; j < 4; ++j)
            Ps[(wv * 16 + lg * 4 + j) * LV + t * 16 + lr] = f2bf(sc[t][j]);
    __syncthreads();

    // PV: ctx (16 x 64 per wave), K padded to 96
    f32x4 co[4] = {};
#pragma unroll
    for (int kk = 0; kk < 3; ++kk) {
        bf16x8 ap = *reinterpret_cast<const bf16x8*>(&Ps[(wv * 16 + lr) * LV + kk * 32 + lg * 8]);
#pragma unroll
        for (int t = 0; t < 4; ++t) {
            bf16x8 bv8 = *reinterpret_cast<const bf16x8*>(&Vt[(t * 16 + lr) * LV + kk * 32 + lg * 8]);
            co[t] = __builtin_amdgcn_mfma_f32_16x16x32_bf16(ap, bv8, co[t], 0, 0, 0);
        }
    }
    // out[b*80 + row][h*64 + col]
    const size_t obase = (size_t)(b * S_ + wv * 16 + lg * 4) * D_ + h * DH;
#pragma unroll
    for (int t = 0; t < 4; ++t)
#pragma unroll
        for (int j = 0; j < 4; ++j)
            out[obase + (size_t)j * D_ + t * 16 + lr] = co[t][j];
}

extern "C" void kernel_launch(void* const* d_in, const int* in_sizes, int n_in,
                              void* d_out, int out_size, void* d_ws, size_t ws_size,
                              hipStream_t stream) {
    const float* hidden = (const float*)d_in[0];
    const int*   mask   = (const int*)d_in[1];
    const float* Wq     = (const float*)d_in[2];
    const float* bq     = (const float*)d_in[3];
    const float* Wk     = (const float*)d_in[4];
    const float* bk     = (const float*)d_in[5];
    const float* Wv     = (const float*)d_in[6];
    const float* bv     = (const float*)d_in[7];
    float* out = (float*)d_out;

    char* ws = (char*)d_ws;
    u16*   Wt    = (u16*)(ws + 0);             // 2304*768*2   = 3,538,944 B
    float* biasf = (float*)(ws + 3538944);     // 2304*4       = 9,216 B
    float* ropeS = (float*)(ws + 3548160);     // 80*32*4      = 10,240 B
    float* ropeC = (float*)(ws + 3558400);     // 10,240 B
    u16*   Y     = (u16*)(ws + 4194304);       // 40960*2304*2 = 188,743,680 B

    prep_kernel<<<dim3(1024), dim3(256), 0, stream>>>(Wq, bq, Wk, bk, Wv, bv, Wt, biasf, ropeS, ropeC);
    qkv_gemm<<<dim3(NQKV / BN, 40960 / BM), dim3(256), 0, stream>>>(hidden, Wt, biasf, Y);
    attn_kernel<<<dim3(H_, B_), dim3(320), 0, stream>>>(Y, mask, ropeS, ropeC, out);
}

// Round 2
// 693.199 us; speedup vs baseline: 1.0837x; 1.0837x over previous
//
#include <hip/hip_runtime.h>
#include <hip/hip_bf16.h>
#include <stdint.h>

#define H_    12
#define B_    512
#define S_    80
#define D_    768
#define NQKV  2304
#define DH    64

typedef __bf16 bf16x8 __attribute__((ext_vector_type(8)));
typedef float  f32x4  __attribute__((ext_vector_type(4)));
typedef unsigned short u16;
typedef unsigned int   u32;

__device__ __forceinline__ u16 f2bf(float f) {
    u32 u = __builtin_bit_cast(u32, f);
    u32 r = u + 0x7FFFu + ((u >> 16) & 1u);
    return (u16)(r >> 16);
}
__device__ __forceinline__ float bf2f(u16 h) {
    u32 u = ((u32)h) << 16;
    return __builtin_bit_cast(float, u);
}

// ---------------- prep: pack W^T (bf16), bias (f32), rope tables ----------------
__global__ void prep_kernel(const float* __restrict__ Wq, const float* __restrict__ bq,
                            const float* __restrict__ Wk, const float* __restrict__ bk,
                            const float* __restrict__ Wv, const float* __restrict__ bv,
                            u16* __restrict__ Wt, float* __restrict__ biasf,
                            float* __restrict__ ropeS, float* __restrict__ ropeC) {
    int idx = blockIdx.x * blockDim.x + threadIdx.x;
    int stride = gridDim.x * blockDim.x;
    // Wt[n][k] = W[k][n%768]  (n: 0..767 -> Wq, 768..1535 -> Wk, else Wv)
    for (int i = idx; i < NQKV * D_; i += stride) {
        int n = i / D_;
        int k = i - n * D_;
        const float* W; int nn;
        if (n < D_)          { W = Wq; nn = n; }
        else if (n < 2 * D_) { W = Wk; nn = n - D_; }
        else                 { W = Wv; nn = n - 2 * D_; }
        Wt[i] = f2bf(W[k * D_ + nn]);
    }
    for (int i = idx; i < NQKV; i += stride) {
        const float* bsrc; int nn;
        if (i < D_)          { bsrc = bq; nn = i; }
        else if (i < 2 * D_) { bsrc = bk; nn = i - D_; }
        else                 { bsrc = bv; nn = i - 2 * D_; }
        biasf[i] = bsrc[nn];
    }
    for (int i = idx; i < S_ * 32; i += stride) {
        int pos = i >> 5, fi = i & 31;
        float invf = powf(10000.0f, -(float)fi / 32.0f);
        float fr = (float)pos * invf;
        ropeS[i] = sinf(fr);
        ropeC[i] = cosf(fr);
    }
}

// ---------------- fused QKV GEMM: Y[40960][2304] = bf16(X @ [Wq|Wk|Wv] + b) ----------------
#define BM 128
#define BN 128
#define BK 64
#define LDA 72    // padded LDS row stride (bf16 elems) for As/Bs
#define CLD 136   // C-tile LDS stride (u16): 272B, 16B-aligned rows

__global__ __launch_bounds__(256, 2) void qkv_gemm(
    const float* __restrict__ X,     // [40960][768] f32
    const u16*   __restrict__ Wt,    // [2304][768] bf16 (N-major = B^T)
    const float* __restrict__ biasf, // [2304]
    u16*         __restrict__ Y)     // [40960][2304] bf16
{
    __shared__ alignas(16) u16 smem[2 * BM * LDA];  // 36864 B
    u16* As = smem;               // [128][72]
    u16* Bs = smem + BM * LDA;    // [128][72]

    // XCD-aware bijective swizzle: 5760 blocks, 720 consecutive per XCD, N-fastest
    const int orig = blockIdx.x;
    const int swz = (orig & 7) * 720 + (orig >> 3);
    const int m0 = (swz / (NQKV / BN)) * BM;
    const int n0 = (swz % (NQKV / BN)) * BN;

    const int tid = threadIdx.x;
    const int lane = tid & 63;
    const int w  = tid >> 6;        // wave 0..3
    const int wr = (w >> 1) * 64;   // wave sub-tile row
    const int wc = (w & 1) * 64;    // wave sub-tile col
    const int lr = lane & 15;
    const int lg = lane >> 4;

    f32x4 acc[4][4] = {};

    const int ar = tid >> 4;          // A stage: row base 0..15 (16 rows/pass)
    const int ac = (tid & 15) * 4;    // A stage: col (float4)
    const int bn = tid >> 3;          // B stage: row base 0..31 (32 rows/pass)
    const int bc = (tid & 7) * 8;     // B stage: col (8 bf16)

    for (int kt = 0; kt < D_ / BK; ++kt) {
        const int k0 = kt * BK;
        float4 av[8];
#pragma unroll
        for (int p = 0; p < 8; ++p)
            av[p] = *reinterpret_cast<const float4*>(&X[(size_t)(m0 + p * 16 + ar) * D_ + k0 + ac]);
        uint4 bv4[4];
#pragma unroll
        for (int p = 0; p < 4; ++p)
            bv4[p] = *reinterpret_cast<const uint4*>(&Wt[(size_t)(n0 + p * 32 + bn) * D_ + k0 + bc]);

        __syncthreads();   // prior iteration's LDS reads done
#pragma unroll
        for (int p = 0; p < 8; ++p) {
            uint2 u;
            u.x = (u32)f2bf(av[p].x) | ((u32)f2bf(av[p].y) << 16);
            u.y = (u32)f2bf(av[p].z) | ((u32)f2bf(av[p].w) << 16);
            *reinterpret_cast<uint2*>(&As[(p * 16 + ar) * LDA + ac]) = u;
        }
#pragma unroll
        for (int p = 0; p < 4; ++p)
            *reinterpret_cast<uint4*>(&Bs[(p * 32 + bn) * LDA + bc]) = bv4[p];
        __syncthreads();

        bf16x8 af[2][4], bf[2][4];
#pragma unroll
        for (int kk = 0; kk < 2; ++kk) {
#pragma unroll
            for (int i = 0; i < 4; ++i) {
                af[kk][i] = *reinterpret_cast<const bf16x8*>(&As[(wr + i * 16 + lr) * LDA + kk * 32 + lg * 8]);
                bf[kk][i] = *reinterpret_cast<const bf16x8*>(&Bs[(wc + i * 16 + lr) * LDA + kk * 32 + lg * 8]);
            }
        }
#pragma unroll
        for (int kk = 0; kk < 2; ++kk)
#pragma unroll
            for (int i = 0; i < 4; ++i)
#pragma unroll
                for (int j = 0; j < 4; ++j)
                    acc[i][j] = __builtin_amdgcn_mfma_f32_16x16x32_bf16(af[kk][i], bf[kk][j], acc[i][j], 0, 0, 0);
    }

    // ---- epilogue: bias + bf16 C-tile to LDS, then fully-coalesced 16B stores ----
    __syncthreads();   // all K-loop LDS reads complete before overwriting smem
    u16* Cs = smem;    // [128][CLD], 34816 B <= 36864
#pragma unroll
    for (int j = 0; j < 4; ++j) {
        int colc = wc + j * 16 + lr;
        float bval = biasf[n0 + colc];
#pragma unroll
        for (int i = 0; i < 4; ++i) {
            int rowb = wr + i * 16 + lg * 4;
#pragma unroll
            for (int r = 0; r < 4; ++r)
                Cs[(rowb + r) * CLD + colc] = f2bf(acc[i][j][r] + bval);
        }
    }
    __syncthreads();
#pragma unroll
    for (int p = 0; p < 8; ++p) {
        int c = p * 256 + tid;
        int row = c >> 4, c8 = c & 15;
        uint4 v = *reinterpret_cast<const uint4*>(&Cs[row * CLD + c8 * 8]);
        *reinterpret_cast<uint4*>(&Y[(size_t)(m0 + row) * NQKV + n0 + c8 * 8]) = v;
    }
}

// ---------------- attention: one block per (b,h), 5 waves (16 q-rows each) ----------------
#define LQ 72    // LDS row stride for Q/K (64 + 8 pad)
#define LV 104   // LDS row stride for Vt/P (96 zero-padded K + 8 pad)

__global__ __launch_bounds__(320) void attn_kernel(
    const u16* __restrict__ Y,      // [40960][2304] bf16 QKV
    const int* __restrict__ mask,   // [512][80]
    const float* __restrict__ ropeS,
    const float* __restrict__ ropeC,
    float* __restrict__ out)        // [40960][768] f32
{
    __shared__ alignas(16) u16 Qs[S_ * LQ];
    __shared__ alignas(16) u16 Ks[S_ * LQ];
    __shared__ alignas(16) u16 Vt[DH * LV];
    __shared__ alignas(16) u16 Ps[5 * 16 * LV];
    __shared__ float biasS[S_];

    const int h = blockIdx.x;
    const int b = blockIdx.y;
    const int tid = threadIdx.x;
    const size_t rowbase = (size_t)b * S_ * NQKV;

    // stage Q (rope + 1/sqrt(dh)) and K (rope)
    for (int p = tid; p < S_ * 32; p += 320) {
        int q = p >> 5, i2 = p & 31;
        u32 uq = *reinterpret_cast<const u32*>(&Y[rowbase + (size_t)q * NQKV + h * DH + 2 * i2]);
        u32 uk = *reinterpret_cast<const u32*>(&Y[rowbase + (size_t)q * NQKV + D_ + h * DH + 2 * i2]);
        float sn = ropeS[p], cs = ropeC[p];
        float q1 = bf2f((u16)(uq & 0xffff)), q2 = bf2f((u16)(uq >> 16));
        float k1 = bf2f((u16)(uk & 0xffff)), k2 = bf2f((u16)(uk >> 16));
        float o1 = (q1 * cs - q2 * sn) * 0.125f;
        float o2 = (q2 * cs + q1 * sn) * 0.125f;
        *reinterpret_cast<u32*>(&Qs[q * LQ + 2 * i2]) = (u32)f2bf(o1) | ((u32)f2bf(o2) << 16);
        o1 = k1 * cs - k2 * sn;
        o2 = k2 * cs + k1 * sn;
        *reinterpret_cast<u32*>(&Ks[q * LQ + 2 * i2]) = (u32)f2bf(o1) | ((u32)f2bf(o2) << 16);
    }
    // stage V transposed: Vt[c][s]
    for (int e = tid; e < S_ * DH; e += 320) {
        int s = e >> 6, c = e & 63;
        Vt[c * LV + s] = Y[rowbase + (size_t)s * NQKV + 2 * D_ + h * DH + c];
    }
    // zero pads: Vt cols 80..103, all of Ps
    for (int e = tid; e < DH * (LV - S_); e += 320) {
        int c = e / (LV - S_), kk = e % (LV - S_);
        Vt[c * LV + S_ + kk] = 0;
    }
    for (int e = tid; e < 5 * 16 * LV; e += 320) Ps[e] = 0;
    for (int e = tid; e < S_; e += 320)
        biasS[e] = (1.0f - (float)mask[b * S_ + e]) * -10000.0f;
    __syncthreads();

    const int wv = tid >> 6;   // stripe 0..4
    const int lane = tid & 63;
    const int lr = lane & 15;
    const int lg = lane >> 4;

    // scores: S = (Q/8) K^T  (16 x 80 per wave)
    f32x4 sc[5] = {};
    bf16x8 aq[2];
#pragma unroll
    for (int kk = 0; kk < 2; ++kk)
        aq[kk] = *reinterpret_cast<const bf16x8*>(&Qs[(wv * 16 + lr) * LQ + kk * 32 + lg * 8]);
#pragma unroll
    for (int t = 0; t < 5; ++t) {
#pragma unroll
        for (int kk = 0; kk < 2; ++kk) {
            bf16x8 bk8 = *reinterpret_cast<const bf16x8*>(&Ks[(t * 16 + lr) * LQ + kk * 32 + lg * 8]);
            sc[t] = __builtin_amdgcn_mfma_f32_16x16x32_bf16(aq[kk], bk8, sc[t], 0, 0, 0);
        }
    }
    // mask bias + softmax per row (4 rows/lane), reductions across 16 lanes
#pragma unroll
    for (int j = 0; j < 4; ++j) {
        float m = -1e30f;
#pragma unroll
        for (int t = 0; t < 5; ++t) { sc[t][j] += biasS[t * 16 + lr]; m = fmaxf(m, sc[t][j]); }
#pragma unroll
        for (int msk = 1; msk < 16; msk <<= 1) m = fmaxf(m, __shfl_xor(m, msk));
        float s = 0.f;
#pragma unroll
        for (int t = 0; t < 5; ++t) { float e = __expf(sc[t][j] - m); sc[t][j] = e; s += e; }
#pragma unroll
        for (int msk = 1; msk < 16; msk <<= 1) s += __shfl_xor(s, msk);
        float ri = 1.0f / s;
#pragma unroll
        for (int t = 0; t < 5; ++t) sc[t][j] *= ri;
    }
    // P -> LDS bf16 (cols 80..95 stay zero)
#pragma unroll
    for (int t = 0; t < 5; ++t)
#pragma unroll
        for (int j = 0; j < 4; ++j)
            Ps[(wv * 16 + lg * 4 + j) * LV + t * 16 + lr] = f2bf(sc[t][j]);
    __syncthreads();

    // PV: ctx (16 x 64 per wave), K padded to 96
    f32x4 co[4] = {};
#pragma unroll
    for (int kk = 0; kk < 3; ++kk) {
        bf16x8 ap = *reinterpret_cast<const bf16x8*>(&Ps[(wv * 16 + lr) * LV + kk * 32 + lg * 8]);
#pragma unroll
        for (int t = 0; t < 4; ++t) {
            bf16x8 bv8 = *reinterpret_cast<const bf16x8*>(&Vt[(t * 16 + lr) * LV + kk * 32 + lg * 8]);
            co[t] = __builtin_amdgcn_mfma_f32_16x16x32_bf16(ap, bv8, co[t], 0, 0, 0);
        }
    }
    // out[b*80 + row][h*64 + col]
    const size_t obase = (size_t)(b * S_ + wv * 16 + lg * 4) * D_ + h * DH;
#pragma unroll
    for (int t = 0; t < 4; ++t)
#pragma unroll
        for (int j = 0; j < 4; ++j)
            out[obase + (size_t)j * D_ + t * 16 + lr] = co[t][j];
}

extern "C" void kernel_launch(void* const* d_in, const int* in_sizes, int n_in,
                              void* d_out, int out_size, void* d_ws, size_t ws_size,
                              hipStream_t stream) {
    const float* hidden = (const float*)d_in[0];
    const int*   mask   = (const int*)d_in[1];
    const float* Wq     = (const float*)d_in[2];
    const float* bq     = (const float*)d_in[3];
    const float* Wk     = (const float*)d_in[4];
    const float* bk     = (const float*)d_in[5];
    const float* Wv     = (const float*)d_in[6];
    const float* bv     = (const float*)d_in[7];
    float* out = (float*)d_out;

    char* ws = (char*)d_ws;
    u16*   Wt    = (u16*)(ws + 0);             // 2304*768*2   = 3,538,944 B
    float* biasf = (float*)(ws + 3538944);     // 2304*4       = 9,216 B
    float* ropeS = (float*)(ws + 3548160);     // 80*32*4      = 10,240 B
    float* ropeC = (float*)(ws + 3558400);     // 10,240 B
    u16*   Y     = (u16*)(ws + 4194304);       // 40960*2304*2 = 188,743,680 B

    prep_kernel<<<dim3(1024), dim3(256), 0, stream>>>(Wq, bq, Wk, bk, Wv, bv, Wt, biasf, ropeS, ropeC);
    qkv_gemm<<<dim3((40960 / BM) * (NQKV / BN)), dim3(256), 0, stream>>>(hidden, Wt, biasf, Y);
    attn_kernel<<<dim3(H_, B_), dim3(320), 0, stream>>>(Y, mask, ropeS, ropeC, out);
}

// Round 3
// 416.936 us; speedup vs baseline: 1.8018x; 1.6626x over previous
//
#include <hip/hip_runtime.h>
#include <hip/hip_bf16.h>
#include <stdint.h>

#define H_    12
#define B_    512
#define S_    80
#define D_    768
#define NQKV  2304
#define DH    64

typedef __bf16 bf16x8 __attribute__((ext_vector_type(8)));
typedef float  f32x4  __attribute__((ext_vector_type(4)));
typedef unsigned short u16;
typedef unsigned int   u32;

__device__ __forceinline__ u16 f2bf(float f) {
    u32 u = __builtin_bit_cast(u32, f);
    u32 r = u + 0x7FFFu + ((u >> 16) & 1u);
    return (u16)(r >> 16);
}
__device__ __forceinline__ float bf2f(u16 h) {
    u32 u = ((u32)h) << 16;
    return __builtin_bit_cast(float, u);
}

// async global->LDS, 16B per lane; LDS dest must be wave-uniform base (HW adds lane*16)
__device__ __forceinline__ void gload16(const void* g, void* l) {
    __builtin_amdgcn_global_load_lds((const __attribute__((address_space(1))) void*)g,
                                     (__attribute__((address_space(3))) void*)l, 16, 0, 0);
}

// ---------------- prep: pack W^T (bf16), bias (f32), rope tables ----------------
__global__ void prep_kernel(const float* __restrict__ Wq, const float* __restrict__ bq,
                            const float* __restrict__ Wk, const float* __restrict__ bk,
                            const float* __restrict__ Wv, const float* __restrict__ bv,
                            u16* __restrict__ Wt, float* __restrict__ biasf,
                            float* __restrict__ ropeS, float* __restrict__ ropeC) {
    int idx = blockIdx.x * blockDim.x + threadIdx.x;
    int stride = gridDim.x * blockDim.x;
    for (int i = idx; i < NQKV * D_; i += stride) {
        int n = i / D_;
        int k = i - n * D_;
        const float* W; int nn;
        if (n < D_)          { W = Wq; nn = n; }
        else if (n < 2 * D_) { W = Wk; nn = n - D_; }
        else                 { W = Wv; nn = n - 2 * D_; }
        Wt[i] = f2bf(W[k * D_ + nn]);
    }
    for (int i = idx; i < NQKV; i += stride) {
        const float* bsrc; int nn;
        if (i < D_)          { bsrc = bq; nn = i; }
        else if (i < 2 * D_) { bsrc = bk; nn = i - D_; }
        else                 { bsrc = bv; nn = i - 2 * D_; }
        biasf[i] = bsrc[nn];
    }
    for (int i = idx; i < S_ * 32; i += stride) {
        int pos = i >> 5, fi = i & 31;
        float invf = powf(10000.0f, -(float)fi / 32.0f);
        float fr = (float)pos * invf;
        ropeS[i] = sinf(fr);
        ropeC[i] = cosf(fr);
    }
}

// ---------------- convert X f32 -> bf16 (once; GEMM then reads bf16 via global_load_lds) ----------------
__global__ void convert_x(const float* __restrict__ X, u16* __restrict__ Xb) {
    int idx = blockIdx.x * blockDim.x + threadIdx.x;
    int stride = gridDim.x * blockDim.x;
    const int n4 = 40960 * D_ / 4;
    for (int i = idx; i < n4; i += stride) {
        float4 v = reinterpret_cast<const float4*>(X)[i];
        uint2 u;
        u.x = (u32)f2bf(v.x) | ((u32)f2bf(v.y) << 16);
        u.y = (u32)f2bf(v.z) | ((u32)f2bf(v.w) << 16);
        reinterpret_cast<uint2*>(Xb)[i] = u;
    }
}

// ---------------- fused QKV GEMM (m97 structure): Y = bf16(Xb @ [Wq|Wk|Wv] + b) ----------------
#define BM 128
#define BN 128
#define BK 64
#define CLD 136   // C-tile LDS stride (u16) for epilogue

__global__ __launch_bounds__(256) void qkv_gemm(
    const u16*   __restrict__ Xb,    // [40960][768] bf16
    const u16*   __restrict__ Wt,    // [2304][768] bf16 (N-major = B^T)
    const float* __restrict__ biasf, // [2304]
    u16*         __restrict__ Y)     // [40960][2304] bf16
{
    __shared__ alignas(16) u16 smem[BM * CLD];   // 34816 B; K-loop uses first 32KB
    u16* As = smem;                 // [128][64] linear
    u16* Bs = smem + BM * BK;       // [128][64] linear

    // XCD-aware bijective swizzle: 5760 blocks = 8 XCDs x 720, N-fastest within XCD
    const int orig = blockIdx.x;
    const int swz = (orig & 7) * 720 + (orig >> 3);
    const int m0 = (swz / (NQKV / BN)) * BM;
    const int n0 = (swz % (NQKV / BN)) * BN;

    const int tid = threadIdx.x;
    const int lane = tid & 63;
    const int w  = tid >> 6;        // wave 0..3
    const int wr = (w >> 1) * 64;
    const int wc = (w & 1) * 64;
    const int lr = lane & 15;
    const int lg = lane >> 4;

    f32x4 acc[4][4] = {};

    const int crow = tid >> 3;      // staging: row 0..31 per pass-group (8 chunks/row)
    const int cc8  = tid & 7;       // staging: 16B chunk within row

    for (int kt = 0; kt < D_ / BK; ++kt) {
        const int k0 = kt * BK;
        // stage A,B tiles: 4 passes each, 256 lanes x 16B; LDS dest wave-uniform
#pragma unroll
        for (int pass = 0; pass < 4; ++pass) {
            gload16(&Xb[(size_t)(m0 + pass * 32 + crow) * D_ + k0 + cc8 * 8],
                    &As[(pass * 256 + w * 64) * 8]);
        }
#pragma unroll
        for (int pass = 0; pass < 4; ++pass) {
            gload16(&Wt[(size_t)(n0 + pass * 32 + crow) * D_ + k0 + cc8 * 8],
                    &Bs[(pass * 256 + w * 64) * 8]);
        }
        __syncthreads();   // drains DMA (vmcnt) + prior ds_reads

        bf16x8 af[2][4], bfr[2][4];
#pragma unroll
        for (int kk = 0; kk < 2; ++kk) {
#pragma unroll
            for (int i = 0; i < 4; ++i) {
                af[kk][i]  = *reinterpret_cast<const bf16x8*>(&As[(wr + i * 16 + lr) * BK + kk * 32 + lg * 8]);
                bfr[kk][i] = *reinterpret_cast<const bf16x8*>(&Bs[(wc + i * 16 + lr) * BK + kk * 32 + lg * 8]);
            }
        }
#pragma unroll
        for (int kk = 0; kk < 2; ++kk)
#pragma unroll
            for (int i = 0; i < 4; ++i)
#pragma unroll
                for (int j = 0; j < 4; ++j)
                    acc[i][j] = __builtin_amdgcn_mfma_f32_16x16x32_bf16(af[kk][i], bfr[kk][j], acc[i][j], 0, 0, 0);
        __syncthreads();   // protect LDS before next stage
    }

    // ---- epilogue: bias + bf16 C-tile to LDS, then fully-coalesced 16B stores ----
    u16* Cs = smem;
#pragma unroll
    for (int j = 0; j < 4; ++j) {
        int colc = wc + j * 16 + lr;
        float bval = biasf[n0 + colc];
#pragma unroll
        for (int i = 0; i < 4; ++i) {
            int rowb = wr + i * 16 + lg * 4;
#pragma unroll
            for (int r = 0; r < 4; ++r)
                Cs[(rowb + r) * CLD + colc] = f2bf(acc[i][j][r] + bval);
        }
    }
    __syncthreads();
#pragma unroll
    for (int p = 0; p < 8; ++p) {
        int c = p * 256 + tid;
        int row = c >> 4, c8 = c & 15;
        uint4 v = *reinterpret_cast<const uint4*>(&Cs[row * CLD + c8 * 8]);
        *reinterpret_cast<uint4*>(&Y[(size_t)(m0 + row) * NQKV + n0 + c8 * 8]) = v;
    }
}

// ---------------- attention: one block per (b,h), 5 waves (16 q-rows each) ----------------
#define LQ 72    // LDS row stride for Q/K (64 + 8 pad)
#define LV 104   // LDS row stride for Vt/P (96 zero-padded K + 8 pad)

__global__ __launch_bounds__(320) void attn_kernel(
    const u16* __restrict__ Y,      // [40960][2304] bf16 QKV
    const int* __restrict__ mask,   // [512][80]
    const float* __restrict__ ropeS,
    const float* __restrict__ ropeC,
    float* __restrict__ out)        // [40960][768] f32
{
    __shared__ alignas(16) u16 Qs[S_ * LQ];
    __shared__ alignas(16) u16 Ks[S_ * LQ];
    __shared__ alignas(16) u16 Vt[DH * LV];
    __shared__ alignas(16) u16 Ps[5 * 16 * LV];
    __shared__ float biasS[S_];

    const int h = blockIdx.x;
    const int b = blockIdx.y;
    const int tid = threadIdx.x;
    const size_t rowbase = (size_t)b * S_ * NQKV;

    for (int p = tid; p < S_ * 32; p += 320) {
        int q = p >> 5, i2 = p & 31;
        u32 uq = *reinterpret_cast<const u32*>(&Y[rowbase + (size_t)q * NQKV + h * DH + 2 * i2]);
        u32 uk = *reinterpret_cast<const u32*>(&Y[rowbase + (size_t)q * NQKV + D_ + h * DH + 2 * i2]);
        float sn = ropeS[p], cs = ropeC[p];
        float q1 = bf2f((u16)(uq & 0xffff)), q2 = bf2f((u16)(uq >> 16));
        float k1 = bf2f((u16)(uk & 0xffff)), k2 = bf2f((u16)(uk >> 16));
        float o1 = (q1 * cs - q2 * sn) * 0.125f;
        float o2 = (q2 * cs + q1 * sn) * 0.125f;
        *reinterpret_cast<u32*>(&Qs[q * LQ + 2 * i2]) = (u32)f2bf(o1) | ((u32)f2bf(o2) << 16);
        o1 = k1 * cs - k2 * sn;
        o2 = k2 * cs + k1 * sn;
        *reinterpret_cast<u32*>(&Ks[q * LQ + 2 * i2]) = (u32)f2bf(o1) | ((u32)f2bf(o2) << 16);
    }
    for (int e = tid; e < S_ * DH; e += 320) {
        int s = e >> 6, c = e & 63;
        Vt[c * LV + s] = Y[rowbase + (size_t)s * NQKV + 2 * D_ + h * DH + c];
    }
    for (int e = tid; e < DH * (LV - S_); e += 320) {
        int c = e / (LV - S_), kk = e % (LV - S_);
        Vt[c * LV + S_ + kk] = 0;
    }
    for (int e = tid; e < 5 * 16 * LV; e += 320) Ps[e] = 0;
    for (int e = tid; e < S_; e += 320)
        biasS[e] = (1.0f - (float)mask[b * S_ + e]) * -10000.0f;
    __syncthreads();

    const int wv = tid >> 6;
    const int lane = tid & 63;
    const int lr = lane & 15;
    const int lg = lane >> 4;

    f32x4 sc[5] = {};
    bf16x8 aq[2];
#pragma unroll
    for (int kk = 0; kk < 2; ++kk)
        aq[kk] = *reinterpret_cast<const bf16x8*>(&Qs[(wv * 16 + lr) * LQ + kk * 32 + lg * 8]);
#pragma unroll
    for (int t = 0; t < 5; ++t) {
#pragma unroll
        for (int kk = 0; kk < 2; ++kk) {
            bf16x8 bk8 = *reinterpret_cast<const bf16x8*>(&Ks[(t * 16 + lr) * LQ + kk * 32 + lg * 8]);
            sc[t] = __builtin_amdgcn_mfma_f32_16x16x32_bf16(aq[kk], bk8, sc[t], 0, 0, 0);
        }
    }
#pragma unroll
    for (int j = 0; j < 4; ++j) {
        float m = -1e30f;
#pragma unroll
        for (int t = 0; t < 5; ++t) { sc[t][j] += biasS[t * 16 + lr]; m = fmaxf(m, sc[t][j]); }
#pragma unroll
        for (int msk = 1; msk < 16; msk <<= 1) m = fmaxf(m, __shfl_xor(m, msk));
        float s = 0.f;
#pragma unroll
        for (int t = 0; t < 5; ++t) { float e = __expf(sc[t][j] - m); sc[t][j] = e; s += e; }
#pragma unroll
        for (int msk = 1; msk < 16; msk <<= 1) s += __shfl_xor(s, msk);
        float ri = 1.0f / s;
#pragma unroll
        for (int t = 0; t < 5; ++t) sc[t][j] *= ri;
    }
#pragma unroll
    for (int t = 0; t < 5; ++t)
#pragma unroll
        for (int j = 0; j < 4; ++j)
            Ps[(wv * 16 + lg * 4 + j) * LV + t * 16 + lr] = f2bf(sc[t][j]);
    __syncthreads();

    f32x4 co[4] = {};
#pragma unroll
    for (int kk = 0; kk < 3; ++kk) {
        bf16x8 ap = *reinterpret_cast<const bf16x8*>(&Ps[(wv * 16 + lr) * LV + kk * 32 + lg * 8]);
#pragma unroll
        for (int t = 0; t < 4; ++t) {
            bf16x8 bv8 = *reinterpret_cast<const bf16x8*>(&Vt[(t * 16 + lr) * LV + kk * 32 + lg * 8]);
            co[t] = __builtin_amdgcn_mfma_f32_16x16x32_bf16(ap, bv8, co[t], 0, 0, 0);
        }
    }
    const size_t obase = (size_t)(b * S_ + wv * 16 + lg * 4) * D_ + h * DH;
#pragma unroll
    for (int t = 0; t < 4; ++t)
#pragma unroll
        for (int j = 0; j < 4; ++j)
            out[obase + (size_t)j * D_ + t * 16 + lr] = co[t][j];
}

extern "C" void kernel_launch(void* const* d_in, const int* in_sizes, int n_in,
                              void* d_out, int out_size, void* d_ws, size_t ws_size,
                              hipStream_t stream) {
    const float* hidden = (const float*)d_in[0];
    const int*   mask   = (const int*)d_in[1];
    const float* Wq     = (const float*)d_in[2];
    const float* bq     = (const float*)d_in[3];
    const float* Wk     = (const float*)d_in[4];
    const float* bk     = (const float*)d_in[5];
    const float* Wv     = (const float*)d_in[6];
    const float* bv     = (const float*)d_in[7];
    float* out = (float*)d_out;

    char* ws = (char*)d_ws;
    u16*   Wt    = (u16*)(ws + 0);             // 3,538,944 B
    float* biasf = (float*)(ws + 3538944);
    float* ropeS = (float*)(ws + 3548160);
    float* ropeC = (float*)(ws + 3558400);
    u16*   Y     = (u16*)(ws + 4194304);       // 188,743,680 B

    // Xb (bf16 X, 63 MB) lives in d_out (126 MB): written before GEMM,
    // only overwritten by attn at the very end (attn doesn't read Xb).
    u16* Xb = (u16*)d_out;

    prep_kernel<<<dim3(1024), dim3(256), 0, stream>>>(Wq, bq, Wk, bk, Wv, bv, Wt, biasf, ropeS, ropeC);
    convert_x<<<dim3(2048), dim3(256), 0, stream>>>(hidden, Xb);
    qkv_gemm<<<dim3((40960 / BM) * (NQKV / BN)), dim3(256), 0, stream>>>(Xb, Wt, biasf, Y);
    attn_kernel<<<dim3(H_, B_), dim3(320), 0, stream>>>(Y, mask, ropeS, ropeC, out);
}

// Round 4
// 331.477 us; speedup vs baseline: 2.2663x; 1.2578x over previous
//
#include <hip/hip_runtime.h>
#include <hip/hip_bf16.h>
#include <stdint.h>

#define H_    12
#define B_    512
#define S_    80
#define D_    768
#define NQKV  2304
#define DH    64

typedef __bf16 bf16x8 __attribute__((ext_vector_type(8)));
typedef float  f32x4  __attribute__((ext_vector_type(4)));
typedef unsigned short u16;
typedef unsigned int   u32;

__device__ __forceinline__ u16 f2bf(float f) {
    u32 u = __builtin_bit_cast(u32, f);
    u32 r = u + 0x7FFFu + ((u >> 16) & 1u);
    return (u16)(r >> 16);
}
__device__ __forceinline__ float bf2f(u16 h) {
    u32 u = ((u32)h) << 16;
    return __builtin_bit_cast(float, u);
}

__device__ __forceinline__ void gload16(const void* g, void* l) {
    __builtin_amdgcn_global_load_lds((const __attribute__((address_space(1))) void*)g,
                                     (__attribute__((address_space(3))) void*)l, 16, 0, 0);
}

#define VMCNT(n) asm volatile("s_waitcnt vmcnt(" #n ")" ::: "memory")
#define BARRIER() do { asm volatile("" ::: "memory"); __builtin_amdgcn_s_barrier(); asm volatile("" ::: "memory"); } while (0)

// ---------------- prep: pack W^T (bf16), bias (f32), rope tables ----------------
__global__ void prep_kernel(const float* __restrict__ Wq, const float* __restrict__ bq,
                            const float* __restrict__ Wk, const float* __restrict__ bk,
                            const float* __restrict__ Wv, const float* __restrict__ bv,
                            u16* __restrict__ Wt, float* __restrict__ biasf,
                            float* __restrict__ ropeS, float* __restrict__ ropeC) {
    int idx = blockIdx.x * blockDim.x + threadIdx.x;
    int stride = gridDim.x * blockDim.x;
    for (int i = idx; i < NQKV * D_; i += stride) {
        int n = i / D_;
        int k = i - n * D_;
        const float* W; int nn;
        if (n < D_)          { W = Wq; nn = n; }
        else if (n < 2 * D_) { W = Wk; nn = n - D_; }
        else                 { W = Wv; nn = n - 2 * D_; }
        Wt[i] = f2bf(W[k * D_ + nn]);
    }
    for (int i = idx; i < NQKV; i += stride) {
        const float* bsrc; int nn;
        if (i < D_)          { bsrc = bq; nn = i; }
        else if (i < 2 * D_) { bsrc = bk; nn = i - D_; }
        else                 { bsrc = bv; nn = i - 2 * D_; }
        biasf[i] = bsrc[nn];
    }
    for (int i = idx; i < S_ * 32; i += stride) {
        int pos = i >> 5, fi = i & 31;
        float invf = powf(10000.0f, -(float)fi / 32.0f);
        float fr = (float)pos * invf;
        ropeS[i] = sinf(fr);
        ropeC[i] = cosf(fr);
    }
}

// ---------------- convert X f32 -> bf16 ----------------
__global__ void convert_x(const float* __restrict__ X, u16* __restrict__ Xb) {
    int idx = blockIdx.x * blockDim.x + threadIdx.x;
    int stride = gridDim.x * blockDim.x;
    const int n4 = 40960 * D_ / 4;
    for (int i = idx; i < n4; i += stride) {
        float4 v = reinterpret_cast<const float4*>(X)[i];
        uint2 u;
        u.x = (u32)f2bf(v.x) | ((u32)f2bf(v.y) << 16);
        u.y = (u32)f2bf(v.z) | ((u32)f2bf(v.w) << 16);
        reinterpret_cast<uint2*>(Xb)[i] = u;
    }
}

// ---------------- QKV GEMM: 256x256 tile, BK=64, 8 waves, 4-phase/K-tile pipelined ----------------
#define BK 64
#define NT 12          // 768 / 64 K-tiles
#define CLD 264        // epilogue C stride (u16)

// LDS layout (u16 elems): buf p at p*32768; A at +0 (half h at h*8192, quarter q at q*4096);
//                         B at +16384 (half hb at hb*8192, jj*4096)
// chunk swizzle: within a 64-col row (8 chunks of 16B), chunk c holds global chunk c ^ (row&7)

__global__ __launch_bounds__(512, 2) void qkv_gemm(
    const u16*   __restrict__ Xb,    // [40960][768] bf16
    const u16*   __restrict__ Wt,    // [2304][768] bf16 (N-major)
    const float* __restrict__ biasf, // [2304]
    u16*         __restrict__ Y)     // [40960][2304] bf16
{
    __shared__ alignas(16) u16 smem[65536];   // 128 KiB

    const int orig = blockIdx.x;
    const int swz = (orig & 7) * 180 + (orig >> 3);   // 1440 = 8 XCD x 180, bijective
    const int m0 = (swz / 9) * 256;
    const int n0 = (swz % 9) * 256;

    const int tid = threadIdx.x;
    const int lane = tid & 63;
    const int w  = tid >> 6;       // 0..7
    const int wr = w >> 2;         // 0..1 (M half)
    const int wc = w & 3;          // 0..3 (N quarter)
    const int lr = lane & 15;
    const int lg = lane >> 4;

    // staging source coords (pre-swizzled global chunk; involution with read-side XOR)
    const int srow = tid >> 3;                       // 0..63
    const int scol = ((tid & 7) ^ (srow & 7)) << 3;  // swizzled col (elems)

    f32x4 acc[8][4] = {};
    bf16x8 af[2][4], bf[2][4];

#define STAGE_A(p, h, q, kt) \
    gload16(&Xb[(size_t)(m0 + (h)*128 + (q)*64 + srow) * D_ + (kt)*BK + scol], \
            &smem[(p)*32768 + (h)*8192 + (q)*4096 + w*512])
#define STAGE_B(p, hb, jj, kt) \
    gload16(&Wt[(size_t)(n0 + (hb)*128 + (jj)*64 + srow) * D_ + (kt)*BK + scol], \
            &smem[(p)*32768 + 16384 + (hb)*8192 + (jj)*4096 + w*512])
#define LDA_F(p, rr, kk_) \
    (*reinterpret_cast<const bf16x8*>(&smem[(p)*32768 + wr*8192 + (rr)*64 + ((((kk_)*4 + lg) ^ ((rr) & 7)) << 3)]))
#define LDB_F(p, rb, kk_) \
    (*reinterpret_cast<const bf16x8*>(&smem[(p)*32768 + 16384 + (wc>>1)*8192 + (rb)*64 + ((((kk_)*4 + lg) ^ ((rb) & 7)) << 3)]))

    // prologue: stage K-tile 0 into buf 0 (order: Aq0, B, Aq1)
    STAGE_A(0, 0, 0, 0); STAGE_A(0, 1, 0, 0);
    STAGE_B(0, 0, 0, 0); STAGE_B(0, 0, 1, 0);
    STAGE_B(0, 1, 0, 0); STAGE_B(0, 1, 1, 0);
    STAGE_A(0, 0, 1, 0); STAGE_A(0, 1, 1, 0);
    VMCNT(2);            // Aq0+B landed; Aq1 (2 loads) in flight
    BARRIER();

#pragma unroll
    for (int u = 0; u < NT - 1; ++u) {
        const int p = u & 1, pn = p ^ 1, kt1 = u + 1;
        // ---- P1: reg af q0 + bf j01 | stage next Aq0 ----
#pragma unroll
        for (int kk = 0; kk < 2; ++kk) {
#pragma unroll
            for (int ii = 0; ii < 4; ++ii) af[kk][ii] = LDA_F(p, ii * 16 + lr, kk);
#pragma unroll
            for (int jj = 0; jj < 2; ++jj) bf[kk][jj] = LDB_F(p, (wc & 1) * 64 + jj * 16 + lr, kk);
        }
        STAGE_A(pn, 0, 0, kt1); STAGE_A(pn, 1, 0, kt1);
        BARRIER();
        __builtin_amdgcn_s_setprio(1);
#pragma unroll
        for (int kk = 0; kk < 2; ++kk)
#pragma unroll
            for (int ii = 0; ii < 4; ++ii)
#pragma unroll
                for (int jj = 0; jj < 2; ++jj)
                    acc[ii][jj] = __builtin_amdgcn_mfma_f32_16x16x32_bf16(af[kk][ii], bf[kk][jj], acc[ii][jj], 0, 0, 0);
        __builtin_amdgcn_s_setprio(0);
        // ---- P2: reg bf j23 | stage next B0 | vmcnt(4) -> current Aq1 landed ----
#pragma unroll
        for (int kk = 0; kk < 2; ++kk)
#pragma unroll
            for (int jj = 2; jj < 4; ++jj) bf[kk][jj] = LDB_F(p, (wc & 1) * 64 + jj * 16 + lr, kk);
        STAGE_B(pn, 0, 0, kt1); STAGE_B(pn, 0, 1, kt1);
        VMCNT(4);
        BARRIER();
        __builtin_amdgcn_s_setprio(1);
#pragma unroll
        for (int kk = 0; kk < 2; ++kk)
#pragma unroll
            for (int ii = 0; ii < 4; ++ii)
#pragma unroll
                for (int jj = 0; jj < 2; ++jj)
                    acc[ii][jj + 2] = __builtin_amdgcn_mfma_f32_16x16x32_bf16(af[kk][ii], bf[kk][jj + 2], acc[ii][jj + 2], 0, 0, 0);
        __builtin_amdgcn_s_setprio(0);
        // ---- P3: reg af q1 | stage next B1 ----
#pragma unroll
        for (int kk = 0; kk < 2; ++kk)
#pragma unroll
            for (int ii = 0; ii < 4; ++ii) af[kk][ii] = LDA_F(p, 64 + ii * 16 + lr, kk);
        STAGE_B(pn, 1, 0, kt1); STAGE_B(pn, 1, 1, kt1);
        BARRIER();
        __builtin_amdgcn_s_setprio(1);
#pragma unroll
        for (int kk = 0; kk < 2; ++kk)
#pragma unroll
            for (int ii = 0; ii < 4; ++ii)
#pragma unroll
                for (int jj = 0; jj < 2; ++jj)
                    acc[ii + 4][jj] = __builtin_amdgcn_mfma_f32_16x16x32_bf16(af[kk][ii], bf[kk][jj], acc[ii + 4][jj], 0, 0, 0);
        __builtin_amdgcn_s_setprio(0);
        // ---- P4: stage next Aq1 | vmcnt(2) -> next Aq0+B landed ----
        STAGE_A(pn, 0, 1, kt1); STAGE_A(pn, 1, 1, kt1);
        VMCNT(2);
        BARRIER();
        __builtin_amdgcn_s_setprio(1);
#pragma unroll
        for (int kk = 0; kk < 2; ++kk)
#pragma unroll
            for (int ii = 0; ii < 4; ++ii)
#pragma unroll
                for (int jj = 0; jj < 2; ++jj)
                    acc[ii + 4][jj + 2] = __builtin_amdgcn_mfma_f32_16x16x32_bf16(af[kk][ii], bf[kk][jj + 2], acc[ii + 4][jj + 2], 0, 0, 0);
        __builtin_amdgcn_s_setprio(0);
    }
    // ---- peeled last tile (p=1), no staging; vmcnt(0) at P2 drains its Aq1 ----
    {
        const int p = 1;
#pragma unroll
        for (int kk = 0; kk < 2; ++kk) {
#pragma unroll
            for (int ii = 0; ii < 4; ++ii) af[kk][ii] = LDA_F(p, ii * 16 + lr, kk);
#pragma unroll
            for (int jj = 0; jj < 2; ++jj) bf[kk][jj] = LDB_F(p, (wc & 1) * 64 + jj * 16 + lr, kk);
        }
        BARRIER();
#pragma unroll
        for (int kk = 0; kk < 2; ++kk)
#pragma unroll
            for (int ii = 0; ii < 4; ++ii)
#pragma unroll
                for (int jj = 0; jj < 2; ++jj)
                    acc[ii][jj] = __builtin_amdgcn_mfma_f32_16x16x32_bf16(af[kk][ii], bf[kk][jj], acc[ii][jj], 0, 0, 0);
#pragma unroll
        for (int kk = 0; kk < 2; ++kk)
#pragma unroll
            for (int jj = 2; jj < 4; ++jj) bf[kk][jj] = LDB_F(p, (wc & 1) * 64 + jj * 16 + lr, kk);
        VMCNT(0);
        BARRIER();
#pragma unroll
        for (int kk = 0; kk < 2; ++kk)
#pragma unroll
            for (int ii = 0; ii < 4; ++ii)
#pragma unroll
                for (int jj = 0; jj < 2; ++jj)
                    acc[ii][jj + 2] = __builtin_amdgcn_mfma_f32_16x16x32_bf16(af[kk][ii], bf[kk][jj + 2], acc[ii][jj + 2], 0, 0, 0);
#pragma unroll
        for (int kk = 0; kk < 2; ++kk)
#pragma unroll
            for (int ii = 0; ii < 4; ++ii) af[kk][ii] = LDA_F(p, 64 + ii * 16 + lr, kk);
        BARRIER();
#pragma unroll
        for (int kk = 0; kk < 2; ++kk)
#pragma unroll
            for (int ii = 0; ii < 4; ++ii)
#pragma unroll
                for (int jj = 0; jj < 2; ++jj)
                    acc[ii + 4][jj] = __builtin_amdgcn_mfma_f32_16x16x32_bf16(af[kk][ii], bf[kk][jj], acc[ii + 4][jj], 0, 0, 0);
        BARRIER();
#pragma unroll
        for (int kk = 0; kk < 2; ++kk)
#pragma unroll
            for (int ii = 0; ii < 4; ++ii)
#pragma unroll
                for (int jj = 0; jj < 2; ++jj)
                    acc[ii + 4][jj + 2] = __builtin_amdgcn_mfma_f32_16x16x32_bf16(af[kk][ii], bf[kk][jj + 2], acc[ii + 4][jj + 2], 0, 0, 0);
    }

    // ---- epilogue: two 128-row halves via LDS, coalesced 16B stores ----
    float bias_v[4];
#pragma unroll
    for (int j = 0; j < 4; ++j) bias_v[j] = biasf[n0 + wc * 64 + j * 16 + lr];

    __syncthreads();   // all LDS reads done (vmcnt already 0)
#pragma unroll
    for (int hh = 0; hh < 2; ++hh) {
        if (wr == hh) {
#pragma unroll
            for (int i = 0; i < 8; ++i)
#pragma unroll
                for (int j = 0; j < 4; ++j)
#pragma unroll
                    for (int r = 0; r < 4; ++r)
                        smem[(i * 16 + lg * 4 + r) * CLD + wc * 64 + j * 16 + lr] = f2bf(acc[i][j][r] + bias_v[j]);
        }
        __syncthreads();
#pragma unroll
        for (int pp = 0; pp < 8; ++pp) {
            int idx = pp * 512 + tid;
            int row = idx >> 5, ch = idx & 31;
            uint4 v = *reinterpret_cast<const uint4*>(&smem[row * CLD + ch * 8]);
            *reinterpret_cast<uint4*>(&Y[(size_t)(m0 + hh * 128 + row) * NQKV + n0 + ch * 8]) = v;
        }
        __syncthreads();
    }
#undef STAGE_A
#undef STAGE_B
#undef LDA_F
#undef LDB_F
}

// ---------------- attention: one block per (b,h), 5 waves (16 q-rows each) ----------------
#define LQ 72
#define LV 104

__global__ __launch_bounds__(320) void attn_kernel(
    const u16* __restrict__ Y,
    const int* __restrict__ mask,
    const float* __restrict__ ropeS,
    const float* __restrict__ ropeC,
    float* __restrict__ out)
{
    __shared__ alignas(16) u16 Qs[S_ * LQ];
    __shared__ alignas(16) u16 Ks[S_ * LQ];
    __shared__ alignas(16) u16 Vt[DH * LV];
    __shared__ alignas(16) u16 Ps[5 * 16 * LV];
    __shared__ float biasS[S_];

    const int h = blockIdx.x;
    const int b = blockIdx.y;
    const int tid = threadIdx.x;
    const size_t rowbase = (size_t)b * S_ * NQKV;

    for (int p = tid; p < S_ * 32; p += 320) {
        int q = p >> 5, i2 = p & 31;
        u32 uq = *reinterpret_cast<const u32*>(&Y[rowbase + (size_t)q * NQKV + h * DH + 2 * i2]);
        u32 uk = *reinterpret_cast<const u32*>(&Y[rowbase + (size_t)q * NQKV + D_ + h * DH + 2 * i2]);
        float sn = ropeS[p], cs = ropeC[p];
        float q1 = bf2f((u16)(uq & 0xffff)), q2 = bf2f((u16)(uq >> 16));
        float k1 = bf2f((u16)(uk & 0xffff)), k2 = bf2f((u16)(uk >> 16));
        float o1 = (q1 * cs - q2 * sn) * 0.125f;
        float o2 = (q2 * cs + q1 * sn) * 0.125f;
        *reinterpret_cast<u32*>(&Qs[q * LQ + 2 * i2]) = (u32)f2bf(o1) | ((u32)f2bf(o2) << 16);
        o1 = k1 * cs - k2 * sn;
        o2 = k2 * cs + k1 * sn;
        *reinterpret_cast<u32*>(&Ks[q * LQ + 2 * i2]) = (u32)f2bf(o1) | ((u32)f2bf(o2) << 16);
    }
    for (int e = tid; e < S_ * DH; e += 320) {
        int s = e >> 6, c = e & 63;
        Vt[c * LV + s] = Y[rowbase + (size_t)s * NQKV + 2 * D_ + h * DH + c];
    }
    for (int e = tid; e < DH * (LV - S_); e += 320) {
        int c = e / (LV - S_), kk = e % (LV - S_);
        Vt[c * LV + S_ + kk] = 0;
    }
    for (int e = tid; e < 5 * 16 * LV; e += 320) Ps[e] = 0;
    for (int e = tid; e < S_; e += 320)
        biasS[e] = (1.0f - (float)mask[b * S_ + e]) * -10000.0f;
    __syncthreads();

    const int wv = tid >> 6;
    const int lane = tid & 63;
    const int lr = lane & 15;
    const int lg = lane >> 4;

    f32x4 sc[5] = {};
    bf16x8 aq[2];
#pragma unroll
    for (int kk = 0; kk < 2; ++kk)
        aq[kk] = *reinterpret_cast<const bf16x8*>(&Qs[(wv * 16 + lr) * LQ + kk * 32 + lg * 8]);
#pragma unroll
    for (int t = 0; t < 5; ++t) {
#pragma unroll
        for (int kk = 0; kk < 2; ++kk) {
            bf16x8 bk8 = *reinterpret_cast<const bf16x8*>(&Ks[(t * 16 + lr) * LQ + kk * 32 + lg * 8]);
            sc[t] = __builtin_amdgcn_mfma_f32_16x16x32_bf16(aq[kk], bk8, sc[t], 0, 0, 0);
        }
    }
#pragma unroll
    for (int j = 0; j < 4; ++j) {
        float m = -1e30f;
#pragma unroll
        for (int t = 0; t < 5; ++t) { sc[t][j] += biasS[t * 16 + lr]; m = fmaxf(m, sc[t][j]); }
#pragma unroll
        for (int msk = 1; msk < 16; msk <<= 1) m = fmaxf(m, __shfl_xor(m, msk));
        float s = 0.f;
#pragma unroll
        for (int t = 0; t < 5; ++t) { float e = __expf(sc[t][j] - m); sc[t][j] = e; s += e; }
#pragma unroll
        for (int msk = 1; msk < 16; msk <<= 1) s += __shfl_xor(s, msk);
        float ri = 1.0f / s;
#pragma unroll
        for (int t = 0; t < 5; ++t) sc[t][j] *= ri;
    }
#pragma unroll
    for (int t = 0; t < 5; ++t)
#pragma unroll
        for (int j = 0; j < 4; ++j)
            Ps[(wv * 16 + lg * 4 + j) * LV + t * 16 + lr] = f2bf(sc[t][j]);
    __syncthreads();

    f32x4 co[4] = {};
#pragma unroll
    for (int kk = 0; kk < 3; ++kk) {
        bf16x8 ap = *reinterpret_cast<const bf16x8*>(&Ps[(wv * 16 + lr) * LV + kk * 32 + lg * 8]);
#pragma unroll
        for (int t = 0; t < 4; ++t) {
            bf16x8 bv8 = *reinterpret_cast<const bf16x8*>(&Vt[(t * 16 + lr) * LV + kk * 32 + lg * 8]);
            co[t] = __builtin_amdgcn_mfma_f32_16x16x32_bf16(ap, bv8, co[t], 0, 0, 0);
        }
    }
    const size_t obase = (size_t)(b * S_ + wv * 16 + lg * 4) * D_ + h * DH;
#pragma unroll
    for (int t = 0; t < 4; ++t)
#pragma unroll
        for (int j = 0; j < 4; ++j)
            out[obase + (size_t)j * D_ + t * 16 + lr] = co[t][j];
}

extern "C" void kernel_launch(void* const* d_in, const int* in_sizes, int n_in,
                              void* d_out, int out_size, void* d_ws, size_t ws_size,
                              hipStream_t stream) {
    const float* hidden = (const float*)d_in[0];
    const int*   mask   = (const int*)d_in[1];
    const float* Wq     = (const float*)d_in[2];
    const float* bq     = (const float*)d_in[3];
    const float* Wk     = (const float*)d_in[4];
    const float* bk     = (const float*)d_in[5];
    const float* Wv     = (const float*)d_in[6];
    const float* bv     = (const float*)d_in[7];
    float* out = (float*)d_out;

    char* ws = (char*)d_ws;
    u16*   Wt    = (u16*)(ws + 0);
    float* biasf = (float*)(ws + 3538944);
    float* ropeS = (float*)(ws + 3548160);
    float* ropeC = (float*)(ws + 3558400);
    u16*   Y     = (u16*)(ws + 4194304);

    u16* Xb = (u16*)d_out;   // bf16 X lives in d_out until attn overwrites it

    prep_kernel<<<dim3(1024), dim3(256), 0, stream>>>(Wq, bq, Wk, bk, Wv, bv, Wt, biasf, ropeS, ropeC);
    convert_x<<<dim3(2048), dim3(256), 0, stream>>>(hidden, Xb);
    qkv_gemm<<<dim3(1440), dim3(512), 0, stream>>>(Xb, Wt, biasf, Y);
    attn_kernel<<<dim3(H_, B_), dim3(320), 0, stream>>>(Y, mask, ropeS, ropeC, out);
}

// Round 5
// 269.813 us; speedup vs baseline: 2.7842x; 1.2285x over previous
//
#include <hip/hip_runtime.h>
#include <hip/hip_bf16.h>
#include <stdint.h>

#define H_    12
#define B_    512
#define S_    80
#define D_    768
#define NQKV  2304
#define DH    64

typedef __bf16 bf16x8 __attribute__((ext_vector_type(8)));
typedef float  f32x4  __attribute__((ext_vector_type(4)));
typedef unsigned short u16;
typedef unsigned int   u32;

__device__ __forceinline__ u16 f2bf(float f) {
    u32 u = __builtin_bit_cast(u32, f);
    u32 r = u + 0x7FFFu + ((u >> 16) & 1u);
    return (u16)(r >> 16);
}
__device__ __forceinline__ float bf2f(u16 h) {
    u32 u = ((u32)h) << 16;
    return __builtin_bit_cast(float, u);
}

__device__ __forceinline__ void gload16(const void* g, void* l) {
    __builtin_amdgcn_global_load_lds((const __attribute__((address_space(1))) void*)g,
                                     (__attribute__((address_space(3))) void*)l, 16, 0, 0);
}

#define VMCNT(n) asm volatile("s_waitcnt vmcnt(" #n ")" ::: "memory")
#define BARRIER() do { asm volatile("" ::: "memory"); __builtin_amdgcn_s_barrier(); asm volatile("" ::: "memory"); } while (0)

// ---------------- prep_fused: W^T via LDS tiles + bias + rope + X->bf16 convert ----------------
#define TRB 432   // 3 mats x 144 transpose tiles
#define CVB 1616  // convert blocks (total grid 2048)

__global__ __launch_bounds__(256) void prep_fused(
    const float* __restrict__ X,
    const float* __restrict__ Wq, const float* __restrict__ bq,
    const float* __restrict__ Wk, const float* __restrict__ bk,
    const float* __restrict__ Wv, const float* __restrict__ bv,
    u16* __restrict__ Wt, float* __restrict__ biasf,
    float* __restrict__ ropeS, float* __restrict__ ropeC,
    u16* __restrict__ Xb)
{
    const int tid = threadIdx.x;
    if (blockIdx.x < TRB) {
        // ---- 64x64 tiled transpose: Wt[mat*768 + n][k] = bf16(W[k][n]) ----
        __shared__ u16 T[64][72];
        int t = blockIdx.x;
        int mat = t / 144;
        int rem = t - mat * 144;
        int kb = (rem / 12) * 64;
        int nb = (rem % 12) * 64;
        const float* W = (mat == 0) ? Wq : (mat == 1 ? Wk : Wv);
        int r  = tid >> 2;      // local k row 0..63
        int q4 = tid & 3;       // 16-col quarter
#pragma unroll
        for (int i = 0; i < 4; ++i) {
            float4 v = *reinterpret_cast<const float4*>(&W[(size_t)(kb + r) * D_ + nb + q4 * 16 + i * 4]);
            T[q4 * 16 + i * 4 + 0][r] = f2bf(v.x);
            T[q4 * 16 + i * 4 + 1][r] = f2bf(v.y);
            T[q4 * 16 + i * 4 + 2][r] = f2bf(v.z);
            T[q4 * 16 + i * 4 + 3][r] = f2bf(v.w);
        }
        __syncthreads();
        int n_local = tid >> 2;
        int kq = tid & 3;
        uint4 o0 = *reinterpret_cast<const uint4*>(&T[n_local][kq * 16]);
        uint4 o1 = *reinterpret_cast<const uint4*>(&T[n_local][kq * 16 + 8]);
        u16* dst = &Wt[(size_t)(mat * D_ + nb + n_local) * D_ + kb + kq * 16];
        *reinterpret_cast<uint4*>(dst) = o0;
        *reinterpret_cast<uint4*>(dst + 8) = o1;
    } else {
        // ---- convert X -> bf16, plus bias and rope tables ----
        int gidx = (blockIdx.x - TRB) * 256 + tid;
        const int gstride = CVB * 256;
        for (int i = gidx; i < NQKV; i += gstride) {
            const float* bsrc; int nn;
            if (i < D_)          { bsrc = bq; nn = i; }
            else if (i < 2 * D_) { bsrc = bk; nn = i - D_; }
            else                 { bsrc = bv; nn = i - 2 * D_; }
            biasf[i] = bsrc[nn];
        }
        for (int i = gidx; i < S_ * 32; i += gstride) {
            int pos = i >> 5, fi = i & 31;
            float invf = powf(10000.0f, -(float)fi / 32.0f);
            float fr = (float)pos * invf;
            ropeS[i] = sinf(fr);
            ropeC[i] = cosf(fr);
        }
        const int n4 = 40960 * D_ / 4;
        for (int i = gidx; i < n4; i += gstride) {
            float4 v = reinterpret_cast<const float4*>(X)[i];
            uint2 u;
            u.x = (u32)f2bf(v.x) | ((u32)f2bf(v.y) << 16);
            u.y = (u32)f2bf(v.z) | ((u32)f2bf(v.w) << 16);
            reinterpret_cast<uint2*>(Xb)[i] = u;
        }
    }
}

// ---------------- QKV GEMM: 256x256 tile, BK=64, 8 waves, 4-phase/K-tile pipelined ----------------
#define BK 64
#define NT 12
#define CLD 264

__global__ __launch_bounds__(512, 2) void qkv_gemm(
    const u16*   __restrict__ Xb,
    const u16*   __restrict__ Wt,
    const float* __restrict__ biasf,
    u16*         __restrict__ Y)
{
    __shared__ alignas(16) u16 smem[65536];

    const int orig = blockIdx.x;
    const int swz = (orig & 7) * 180 + (orig >> 3);
    const int m0 = (swz / 9) * 256;
    const int n0 = (swz % 9) * 256;

    const int tid = threadIdx.x;
    const int lane = tid & 63;
    const int w  = tid >> 6;
    const int wr = w >> 2;
    const int wc = w & 3;
    const int lr = lane & 15;
    const int lg = lane >> 4;

    const int srow = tid >> 3;
    const int scol = ((tid & 7) ^ (srow & 7)) << 3;

    f32x4 acc[8][4] = {};
    bf16x8 af[2][4], bf[2][4];

#define STAGE_A(p, h, q, kt) \
    gload16(&Xb[(size_t)(m0 + (h)*128 + (q)*64 + srow) * D_ + (kt)*BK + scol], \
            &smem[(p)*32768 + (h)*8192 + (q)*4096 + w*512])
#define STAGE_B(p, hb, jj, kt) \
    gload16(&Wt[(size_t)(n0 + (hb)*128 + (jj)*64 + srow) * D_ + (kt)*BK + scol], \
            &smem[(p)*32768 + 16384 + (hb)*8192 + (jj)*4096 + w*512])
#define LDA_F(p, rr, kk_) \
    (*reinterpret_cast<const bf16x8*>(&smem[(p)*32768 + wr*8192 + (rr)*64 + ((((kk_)*4 + lg) ^ ((rr) & 7)) << 3)]))
#define LDB_F(p, rb, kk_) \
    (*reinterpret_cast<const bf16x8*>(&smem[(p)*32768 + 16384 + (wc>>1)*8192 + (rb)*64 + ((((kk_)*4 + lg) ^ ((rb) & 7)) << 3)]))

    STAGE_A(0, 0, 0, 0); STAGE_A(0, 1, 0, 0);
    STAGE_B(0, 0, 0, 0); STAGE_B(0, 0, 1, 0);
    STAGE_B(0, 1, 0, 0); STAGE_B(0, 1, 1, 0);
    STAGE_A(0, 0, 1, 0); STAGE_A(0, 1, 1, 0);
    VMCNT(2);
    BARRIER();

#pragma unroll
    for (int u = 0; u < NT - 1; ++u) {
        const int p = u & 1, pn = p ^ 1, kt1 = u + 1;
#pragma unroll
        for (int kk = 0; kk < 2; ++kk) {
#pragma unroll
            for (int ii = 0; ii < 4; ++ii) af[kk][ii] = LDA_F(p, ii * 16 + lr, kk);
#pragma unroll
            for (int jj = 0; jj < 2; ++jj) bf[kk][jj] = LDB_F(p, (wc & 1) * 64 + jj * 16 + lr, kk);
        }
        STAGE_A(pn, 0, 0, kt1); STAGE_A(pn, 1, 0, kt1);
        BARRIER();
        __builtin_amdgcn_s_setprio(1);
#pragma unroll
        for (int kk = 0; kk < 2; ++kk)
#pragma unroll
            for (int ii = 0; ii < 4; ++ii)
#pragma unroll
                for (int jj = 0; jj < 2; ++jj)
                    acc[ii][jj] = __builtin_amdgcn_mfma_f32_16x16x32_bf16(af[kk][ii], bf[kk][jj], acc[ii][jj], 0, 0, 0);
        __builtin_amdgcn_s_setprio(0);
#pragma unroll
        for (int kk = 0; kk < 2; ++kk)
#pragma unroll
            for (int jj = 2; jj < 4; ++jj) bf[kk][jj] = LDB_F(p, (wc & 1) * 64 + jj * 16 + lr, kk);
        STAGE_B(pn, 0, 0, kt1); STAGE_B(pn, 0, 1, kt1);
        VMCNT(4);
        BARRIER();
        __builtin_amdgcn_s_setprio(1);
#pragma unroll
        for (int kk = 0; kk < 2; ++kk)
#pragma unroll
            for (int ii = 0; ii < 4; ++ii)
#pragma unroll
                for (int jj = 0; jj < 2; ++jj)
                    acc[ii][jj + 2] = __builtin_amdgcn_mfma_f32_16x16x32_bf16(af[kk][ii], bf[kk][jj + 2], acc[ii][jj + 2], 0, 0, 0);
        __builtin_amdgcn_s_setprio(0);
#pragma unroll
        for (int kk = 0; kk < 2; ++kk)
#pragma unroll
            for (int ii = 0; ii < 4; ++ii) af[kk][ii] = LDA_F(p, 64 + ii * 16 + lr, kk);
        STAGE_B(pn, 1, 0, kt1); STAGE_B(pn, 1, 1, kt1);
        BARRIER();
        __builtin_amdgcn_s_setprio(1);
#pragma unroll
        for (int kk = 0; kk < 2; ++kk)
#pragma unroll
            for (int ii = 0; ii < 4; ++ii)
#pragma unroll
                for (int jj = 0; jj < 2; ++jj)
                    acc[ii + 4][jj] = __builtin_amdgcn_mfma_f32_16x16x32_bf16(af[kk][ii], bf[kk][jj], acc[ii + 4][jj], 0, 0, 0);
        __builtin_amdgcn_s_setprio(0);
        STAGE_A(pn, 0, 1, kt1); STAGE_A(pn, 1, 1, kt1);
        VMCNT(2);
        BARRIER();
        __builtin_amdgcn_s_setprio(1);
#pragma unroll
        for (int kk = 0; kk < 2; ++kk)
#pragma unroll
            for (int ii = 0; ii < 4; ++ii)
#pragma unroll
                for (int jj = 0; jj < 2; ++jj)
                    acc[ii + 4][jj + 2] = __builtin_amdgcn_mfma_f32_16x16x32_bf16(af[kk][ii], bf[kk][jj + 2], acc[ii + 4][jj + 2], 0, 0, 0);
        __builtin_amdgcn_s_setprio(0);
    }
    {
        const int p = 1;
#pragma unroll
        for (int kk = 0; kk < 2; ++kk) {
#pragma unroll
            for (int ii = 0; ii < 4; ++ii) af[kk][ii] = LDA_F(p, ii * 16 + lr, kk);
#pragma unroll
            for (int jj = 0; jj < 2; ++jj) bf[kk][jj] = LDB_F(p, (wc & 1) * 64 + jj * 16 + lr, kk);
        }
        BARRIER();
#pragma unroll
        for (int kk = 0; kk < 2; ++kk)
#pragma unroll
            for (int ii = 0; ii < 4; ++ii)
#pragma unroll
                for (int jj = 0; jj < 2; ++jj)
                    acc[ii][jj] = __builtin_amdgcn_mfma_f32_16x16x32_bf16(af[kk][ii], bf[kk][jj], acc[ii][jj], 0, 0, 0);
#pragma unroll
        for (int kk = 0; kk < 2; ++kk)
#pragma unroll
            for (int jj = 2; jj < 4; ++jj) bf[kk][jj] = LDB_F(p, (wc & 1) * 64 + jj * 16 + lr, kk);
        VMCNT(0);
        BARRIER();
#pragma unroll
        for (int kk = 0; kk < 2; ++kk)
#pragma unroll
            for (int ii = 0; ii < 4; ++ii)
#pragma unroll
                for (int jj = 0; jj < 2; ++jj)
                    acc[ii][jj + 2] = __builtin_amdgcn_mfma_f32_16x16x32_bf16(af[kk][ii], bf[kk][jj + 2], acc[ii][jj + 2], 0, 0, 0);
#pragma unroll
        for (int kk = 0; kk < 2; ++kk)
#pragma unroll
            for (int ii = 0; ii < 4; ++ii) af[kk][ii] = LDA_F(p, 64 + ii * 16 + lr, kk);
        BARRIER();
#pragma unroll
        for (int kk = 0; kk < 2; ++kk)
#pragma unroll
            for (int ii = 0; ii < 4; ++ii)
#pragma unroll
                for (int jj = 0; jj < 2; ++jj)
                    acc[ii + 4][jj] = __builtin_amdgcn_mfma_f32_16x16x32_bf16(af[kk][ii], bf[kk][jj], acc[ii + 4][jj], 0, 0, 0);
        BARRIER();
#pragma unroll
        for (int kk = 0; kk < 2; ++kk)
#pragma unroll
            for (int ii = 0; ii < 4; ++ii)
#pragma unroll
                for (int jj = 0; jj < 2; ++jj)
                    acc[ii + 4][jj + 2] = __builtin_amdgcn_mfma_f32_16x16x32_bf16(af[kk][ii], bf[kk][jj + 2], acc[ii + 4][jj + 2], 0, 0, 0);
    }

    float bias_v[4];
#pragma unroll
    for (int j = 0; j < 4; ++j) bias_v[j] = biasf[n0 + wc * 64 + j * 16 + lr];

    __syncthreads();
#pragma unroll
    for (int hh = 0; hh < 2; ++hh) {
        if (wr == hh) {
#pragma unroll
            for (int i = 0; i < 8; ++i)
#pragma unroll
                for (int j = 0; j < 4; ++j)
#pragma unroll
                    for (int r = 0; r < 4; ++r)
                        smem[(i * 16 + lg * 4 + r) * CLD + wc * 64 + j * 16 + lr] = f2bf(acc[i][j][r] + bias_v[j]);
        }
        __syncthreads();
#pragma unroll
        for (int pp = 0; pp < 8; ++pp) {
            int idx = pp * 512 + tid;
            int row = idx >> 5, ch = idx & 31;
            uint4 v = *reinterpret_cast<const uint4*>(&smem[row * CLD + ch * 8]);
            *reinterpret_cast<uint4*>(&Y[(size_t)(m0 + hh * 128 + row) * NQKV + n0 + ch * 8]) = v;
        }
        __syncthreads();
    }
#undef STAGE_A
#undef STAGE_B
#undef LDA_F
#undef LDB_F
}

// ---------------- attention: one block per (b,h), 5 waves (16 q-rows each) ----------------
#define LQ 72
#define LV 104

__device__ __forceinline__ u32 rope_rot(u32 u, float sn, float cs, float scale) {
    float x1 = bf2f((u16)(u & 0xffff)), x2 = bf2f((u16)(u >> 16));
    float o1 = (x1 * cs - x2 * sn) * scale;
    float o2 = (x2 * cs + x1 * sn) * scale;
    return (u32)f2bf(o1) | ((u32)f2bf(o2) << 16);
}

__global__ __launch_bounds__(320) void attn_kernel(
    const u16* __restrict__ Y,
    const int* __restrict__ mask,
    const float* __restrict__ ropeS,
    const float* __restrict__ ropeC,
    float* __restrict__ out)
{
    __shared__ alignas(16) u16 Qs[S_ * LQ];
    __shared__ alignas(16) u16 Ks[S_ * LQ];
    __shared__ alignas(16) u16 Vt[DH * LV];
    __shared__ alignas(16) u16 Ps[5 * 16 * LV];
    __shared__ float biasS[S_];

    const int h = blockIdx.x;
    const int b = blockIdx.y;
    const int tid = threadIdx.x;
    const size_t rowbase = (size_t)b * S_ * NQKV;

    // Q/K: 80 rows x 16 chunks (8 Q + 8 K), 16B each; RoPE fused
#pragma unroll
    for (int it = 0; it < 4; ++it) {
        int ch = it * 320 + tid;
        int q = ch >> 4;
        int sub = ch & 15;
        int isK = sub >> 3;
        int c0 = (sub & 7) * 8;
        uint4 v = *reinterpret_cast<const uint4*>(&Y[rowbase + (size_t)q * NQKV + isK * D_ + h * DH + c0]);
        float4 sn4 = *reinterpret_cast<const float4*>(&ropeS[q * 32 + c0 / 2]);
        float4 cs4 = *reinterpret_cast<const float4*>(&ropeC[q * 32 + c0 / 2]);
        float scale = isK ? 1.0f : 0.125f;
        uint4 o;
        o.x = rope_rot(v.x, sn4.x, cs4.x, scale);
        o.y = rope_rot(v.y, sn4.y, cs4.y, scale);
        o.z = rope_rot(v.z, sn4.z, cs4.z, scale);
        o.w = rope_rot(v.w, sn4.w, cs4.w, scale);
        u16* dst = isK ? Ks : Qs;
        *reinterpret_cast<uint4*>(&dst[q * LQ + c0]) = o;
    }
    // V: 80 rows x 8 chunks, transpose into Vt[c][s]
#pragma unroll
    for (int it = 0; it < 2; ++it) {
        int ch = it * 320 + tid;
        int s = ch >> 3, c0 = (ch & 7) * 8;
        uint4 v = *reinterpret_cast<const uint4*>(&Y[rowbase + (size_t)s * NQKV + 2 * D_ + h * DH + c0]);
        Vt[(c0 + 0) * LV + s] = (u16)(v.x & 0xffff);
        Vt[(c0 + 1) * LV + s] = (u16)(v.x >> 16);
        Vt[(c0 + 2) * LV + s] = (u16)(v.y & 0xffff);
        Vt[(c0 + 3) * LV + s] = (u16)(v.y >> 16);
        Vt[(c0 + 4) * LV + s] = (u16)(v.z & 0xffff);
        Vt[(c0 + 5) * LV + s] = (u16)(v.z >> 16);
        Vt[(c0 + 6) * LV + s] = (u16)(v.w & 0xffff);
        Vt[(c0 + 7) * LV + s] = (u16)(v.w >> 16);
    }
    // zero only the read pad columns (s/k = 80..95)
    for (int e = tid; e < DH * 16; e += 320) {
        int c = e >> 4, s = 80 + (e & 15);
        Vt[c * LV + s] = 0;
    }
    for (int e = tid; e < S_ * 16; e += 320) {
        int row = e >> 4, col = 80 + (e & 15);
        Ps[row * LV + col] = 0;
    }
    for (int e = tid; e < S_; e += 320)
        biasS[e] = (1.0f - (float)mask[b * S_ + e]) * -10000.0f;
    __syncthreads();

    const int wv = tid >> 6;
    const int lane = tid & 63;
    const int lr = lane & 15;
    const int lg = lane >> 4;

    f32x4 sc[5] = {};
    bf16x8 aq[2];
#pragma unroll
    for (int kk = 0; kk < 2; ++kk)
        aq[kk] = *reinterpret_cast<const bf16x8*>(&Qs[(wv * 16 + lr) * LQ + kk * 32 + lg * 8]);
#pragma unroll
    for (int t = 0; t < 5; ++t) {
#pragma unroll
        for (int kk = 0; kk < 2; ++kk) {
            bf16x8 bk8 = *reinterpret_cast<const bf16x8*>(&Ks[(t * 16 + lr) * LQ + kk * 32 + lg * 8]);
            sc[t] = __builtin_amdgcn_mfma_f32_16x16x32_bf16(aq[kk], bk8, sc[t], 0, 0, 0);
        }
    }
#pragma unroll
    for (int j = 0; j < 4; ++j) {
        float m = -1e30f;
#pragma unroll
        for (int t = 0; t < 5; ++t) { sc[t][j] += biasS[t * 16 + lr]; m = fmaxf(m, sc[t][j]); }
#pragma unroll
        for (int msk = 1; msk < 16; msk <<= 1) m = fmaxf(m, __shfl_xor(m, msk));
        float s = 0.f;
#pragma unroll
        for (int t = 0; t < 5; ++t) { float e = __expf(sc[t][j] - m); sc[t][j] = e; s += e; }
#pragma unroll
        for (int msk = 1; msk < 16; msk <<= 1) s += __shfl_xor(s, msk);
        float ri = 1.0f / s;
#pragma unroll
        for (int t = 0; t < 5; ++t) sc[t][j] *= ri;
    }
#pragma unroll
    for (int t = 0; t < 5; ++t)
#pragma unroll
        for (int j = 0; j < 4; ++j)
            Ps[(wv * 16 + lg * 4 + j) * LV + t * 16 + lr] = f2bf(sc[t][j]);
    __syncthreads();

    f32x4 co[4] = {};
#pragma unroll
    for (int kk = 0; kk < 3; ++kk) {
        bf16x8 ap = *reinterpret_cast<const bf16x8*>(&Ps[(wv * 16 + lr) * LV + kk * 32 + lg * 8]);
#pragma unroll
        for (int t = 0; t < 4; ++t) {
            bf16x8 bv8 = *reinterpret_cast<const bf16x8*>(&Vt[(t * 16 + lr) * LV + kk * 32 + lg * 8]);
            co[t] = __builtin_amdgcn_mfma_f32_16x16x32_bf16(ap, bv8, co[t], 0, 0, 0);
        }
    }
    const size_t obase = (size_t)(b * S_ + wv * 16 + lg * 4) * D_ + h * DH;
#pragma unroll
    for (int t = 0; t < 4; ++t)
#pragma unroll
        for (int j = 0; j < 4; ++j)
            out[obase + (size_t)j * D_ + t * 16 + lr] = co[t][j];
}

extern "C" void kernel_launch(void* const* d_in, const int* in_sizes, int n_in,
                              void* d_out, int out_size, void* d_ws, size_t ws_size,
                              hipStream_t stream) {
    const float* hidden = (const float*)d_in[0];
    const int*   mask   = (const int*)d_in[1];
    const float* Wq     = (const float*)d_in[2];
    const float* bq     = (const float*)d_in[3];
    const float* Wk     = (const float*)d_in[4];
    const float* bk     = (const float*)d_in[5];
    const float* Wv     = (const float*)d_in[6];
    const float* bv     = (const float*)d_in[7];
    float* out = (float*)d_out;

    char* ws = (char*)d_ws;
    u16*   Wt    = (u16*)(ws + 0);
    float* biasf = (float*)(ws + 3538944);
    float* ropeS = (float*)(ws + 3548160);
    float* ropeC = (float*)(ws + 3558400);
    u16*   Y     = (u16*)(ws + 4194304);

    u16* Xb = (u16*)d_out;   // bf16 X lives in d_out until attn overwrites it

    prep_fused<<<dim3(TRB + CVB), dim3(256), 0, stream>>>(hidden, Wq, bq, Wk, bk, Wv, bv,
                                                          Wt, biasf, ropeS, ropeC, Xb);
    qkv_gemm<<<dim3(1440), dim3(512), 0, stream>>>(Xb, Wt, biasf, Y);
    attn_kernel<<<dim3(H_, B_), dim3(320), 0, stream>>>(Y, mask, ropeS, ropeC, out);
}